// Round 1
// baseline (619.061 us; speedup 1.0000x reference)
//
#include <hip/hip_runtime.h>
#include <hip/hip_bf16.h>
#include <cstddef>

// ---------------- problem constants ----------------
#define BATCH    16
#define HID      2048
#define NH       16
#define NKV      8
#define HD       128
#define BLKSZ    16
#define MAXB     256
#define LMAX     4096          // MAXB*BLKSZ
#define QSIZE    2048          // NH*HD
#define KVSIZE   1024          // NKV*HD
#define QKVROWS  4096          // QSIZE + 2*KVSIZE
#define KDIM     2048          // GEMM K (both gemms)
#define EPS      1e-6f
#define SCALE    0.08838834764831845f   // 128^-0.5

#define CHUNK    64            // tokens per wave in attention
#define NCHUNK   64            // LMAX / CHUNK
#define PSTRIDE  130           // per-partial floats: m, l, acc[128]

// ---------------- GEMM: out[b][r] = sum_k x[b][k] * w[r][k], M=16 ----------------
__global__ __launch_bounds__(256) void gemm_m16(const float* __restrict__ x,
                                                const float* __restrict__ w,
                                                float* __restrict__ out,
                                                int ostride) {
    __shared__ float wt[16][132];
    __shared__ float ht[16][132];
    const int t  = threadIdx.x;
    const int r  = t >> 4;          // compute row (local)
    const int b  = t & 15;          // compute batch
    const int lr = t >> 4;          // load row (local)
    const int c8 = (t & 15) * 8;    // load col offset
    const int row0 = blockIdx.x * 16;

    const float* wl = w + (size_t)(row0 + lr) * KDIM + c8;
    const float* xl = x + (size_t)lr * KDIM + c8;

    float acc = 0.f;
    for (int kc = 0; kc < KDIM; kc += 128) {
        float4 a0 = *(const float4*)(wl + kc);
        float4 a1 = *(const float4*)(wl + kc + 4);
        float4 b0 = *(const float4*)(xl + kc);
        float4 b1 = *(const float4*)(xl + kc + 4);
        __syncthreads();   // previous iteration's LDS reads complete
        *(float4*)&wt[lr][c8]     = a0;
        *(float4*)&wt[lr][c8 + 4] = a1;
        *(float4*)&ht[lr][c8]     = b0;
        *(float4*)&ht[lr][c8 + 4] = b1;
        __syncthreads();
#pragma unroll
        for (int k = 0; k < 128; k += 4) {
            float4 wv = *(const float4*)&wt[r][k];
            float4 hv = *(const float4*)&ht[b][k];
            acc += wv.x * hv.x + wv.y * hv.y + wv.z * hv.z + wv.w * hv.w;
        }
    }
    out[(size_t)b * ostride + row0 + r] = acc;
}

// ---------------- RMSNorm + RoPE + cache write ----------------
// grid: (32, BATCH), block: 64.  slot s: 0..15 q heads, 16..23 k heads, 24..31 v heads
__global__ __launch_bounds__(64) void norm_rope_cache(float* __restrict__ qkv,
                                                      const float* __restrict__ qw,
                                                      const float* __restrict__ kw,
                                                      const float* __restrict__ cs_cache,
                                                      const int* __restrict__ positions,
                                                      const int* __restrict__ slot_mapping,
                                                      float* __restrict__ k_cache,
                                                      float* __restrict__ v_cache) {
    const int s = blockIdx.x;
    const int b = blockIdx.y;
    const int l = threadIdx.x;   // 0..63, owns dims l and l+64
    float* base = qkv + (size_t)b * QKVROWS;

    if (s < NH) {
        // q head: RMSNorm + RoPE + fold SCALE, in-place
        float* src = base + s * HD;
        float x1 = src[l], x2 = src[l + 64];
        float ss = x1 * x1 + x2 * x2;
#pragma unroll
        for (int m = 1; m < 64; m <<= 1) ss += __shfl_xor(ss, m, 64);
        float inv = rsqrtf(ss * (1.f / 128.f) + EPS);
        x1 = x1 * inv * qw[l];
        x2 = x2 * inv * qw[l + 64];
        int pos = positions[b];
        float c  = cs_cache[(size_t)pos * HD + l];
        float sn = cs_cache[(size_t)pos * HD + 64 + l];
        src[l]      = (x1 * c - x2 * sn) * SCALE;
        src[l + 64] = (x2 * c + x1 * sn) * SCALE;
    } else if (s < NH + NKV) {
        // k head: RMSNorm + RoPE, write to paged cache
        int h = s - NH;
        const float* src = base + QSIZE + h * HD;
        float x1 = src[l], x2 = src[l + 64];
        float ss = x1 * x1 + x2 * x2;
#pragma unroll
        for (int m = 1; m < 64; m <<= 1) ss += __shfl_xor(ss, m, 64);
        float inv = rsqrtf(ss * (1.f / 128.f) + EPS);
        x1 = x1 * inv * kw[l];
        x2 = x2 * inv * kw[l + 64];
        int pos = positions[b];
        float c  = cs_cache[(size_t)pos * HD + l];
        float sn = cs_cache[(size_t)pos * HD + 64 + l];
        int slot = slot_mapping[b];
        float* dst = k_cache + (size_t)slot * KVSIZE + h * HD;
        dst[l]      = x1 * c - x2 * sn;
        dst[l + 64] = x2 * c + x1 * sn;
    } else {
        // v head: plain copy into paged cache
        int h = s - NH - NKV;
        const float* src = base + QSIZE + KVSIZE + h * HD;
        int slot = slot_mapping[b];
        float* dst = v_cache + (size_t)slot * KVSIZE + h * HD;
        dst[l]      = src[l];
        dst[l + 64] = src[l + 64];
    }
}

// ---------------- attention partials (flash-decoding) ----------------
// grid: (NCHUNK/4, NKV, BATCH), block 256 (4 waves, one chunk each).
// wave layout: 16 tokens x 4 lanes; lane owns 32-dim quarter c*32..c*32+31.
__global__ __launch_bounds__(256) void attn_partial(const float* __restrict__ q,
                                                    const float* __restrict__ k_cache,
                                                    const float* __restrict__ v_cache,
                                                    const int* __restrict__ block_tables,
                                                    const int* __restrict__ context_lens,
                                                    float* __restrict__ part) {
    const int b    = blockIdx.z;
    const int kv   = blockIdx.y;
    const int wave = threadIdx.x >> 6;
    const int chunk = blockIdx.x * 4 + wave;
    const int lane = threadIdx.x & 63;
    const int len  = context_lens[b];
    const int start = chunk * CHUNK;
    if (start >= len) return;

    const int t = lane >> 2;   // token within cache block
    const int c = lane & 3;    // dim quarter

    // q fragments for the 2 GQA heads of this kv head (SCALE pre-folded)
    const float* qb = q + (size_t)b * QKVROWS + (2 * kv) * HD + c * 32;
    float q0[32], q1[32];
#pragma unroll
    for (int j = 0; j < 32; j += 4) {
        *(float4*)&q0[j] = *(const float4*)(qb + j);
        *(float4*)&q1[j] = *(const float4*)(qb + HD + j);
    }

    float acc0[32], acc1[32];
#pragma unroll
    for (int j = 0; j < 32; j++) { acc0[j] = 0.f; acc1[j] = 0.f; }
    float m0 = -1e30f, m1 = -1e30f, l0 = 0.f, l1 = 0.f;

    const int* btab = block_tables + b * MAXB;
    const int nblk = min(CHUNK / BLKSZ, (len - start + BLKSZ - 1) >> 4);

    for (int cb = 0; cb < nblk; cb++) {
        const int gb = (start >> 4) + cb;
        const int pb = btab[gb];
        const float* kp = k_cache + ((size_t)pb * BLKSZ + t) * KVSIZE + kv * HD + c * 32;
        const float* vp = v_cache + ((size_t)pb * BLKSZ + t) * KVSIZE + kv * HD + c * 32;
        float4 kx[8], vx[8];
#pragma unroll
        for (int j = 0; j < 8; j++) kx[j] = ((const float4*)kp)[j];
#pragma unroll
        for (int j = 0; j < 8; j++) vx[j] = ((const float4*)vp)[j];

        float s0 = 0.f, s1 = 0.f;
#pragma unroll
        for (int j = 0; j < 8; j++) {
            const float* kk = (const float*)&kx[j];
#pragma unroll
            for (int e = 0; e < 4; e++) {
                s0 += q0[4 * j + e] * kk[e];
                s1 += q1[4 * j + e] * kk[e];
            }
        }
        // reduce over the 4-lane dim group
        s0 += __shfl_xor(s0, 1, 64); s0 += __shfl_xor(s0, 2, 64);
        s1 += __shfl_xor(s1, 1, 64); s1 += __shfl_xor(s1, 2, 64);

        const int gidx = start + cb * BLKSZ + t;
        if (gidx >= len) { s0 = -1e30f; s1 = -1e30f; }

        // wave max (token groups differ only at masks >= 4)
        float bm0 = s0, bm1 = s1;
#pragma unroll
        for (int m = 4; m < 64; m <<= 1) {
            bm0 = fmaxf(bm0, __shfl_xor(bm0, m, 64));
            bm1 = fmaxf(bm1, __shfl_xor(bm1, m, 64));
        }
        const float nm0 = fmaxf(m0, bm0), nm1 = fmaxf(m1, bm1);
        const float a0 = __expf(m0 - nm0), a1 = __expf(m1 - nm1);
        const float p0 = __expf(s0 - nm0), p1 = __expf(s1 - nm1);
        m0 = nm0; m1 = nm1;
        l0 = l0 * a0 + p0;
        l1 = l1 * a1 + p1;
#pragma unroll
        for (int j = 0; j < 8; j++) {
            const float* vv = (const float*)&vx[j];
#pragma unroll
            for (int e = 0; e < 4; e++) {
                acc0[4 * j + e] = acc0[4 * j + e] * a0 + p0 * vv[e];
                acc1[4 * j + e] = acc1[4 * j + e] * a1 + p1 * vv[e];
            }
        }
    }

    // reduce V accumulators across the 16 token groups
#pragma unroll
    for (int m = 4; m < 64; m <<= 1) {
#pragma unroll
        for (int j = 0; j < 32; j++) {
            acc0[j] += __shfl_xor(acc0[j], m, 64);
            acc1[j] += __shfl_xor(acc1[j], m, 64);
        }
    }
    // l: every token's p was added by its 4 lanes -> sum/4
#pragma unroll
    for (int m = 1; m < 64; m <<= 1) {
        l0 += __shfl_xor(l0, m, 64);
        l1 += __shfl_xor(l1, m, 64);
    }
    l0 *= 0.25f; l1 *= 0.25f;

    float* pp0 = part + (size_t)(((b * NKV + kv) * NCHUNK + chunk) * 2 + 0) * PSTRIDE;
    float* pp1 = pp0 + PSTRIDE;
    if (t == 0) {   // lanes 0..3 hold the full reduced accumulators
#pragma unroll
        for (int j = 0; j < 32; j++) {
            pp0[2 + c * 32 + j] = acc0[j];
            pp1[2 + c * 32 + j] = acc1[j];
        }
        if (c == 0) {
            pp0[0] = m0; pp0[1] = l0;
            pp1[0] = m1; pp1[1] = l1;
        }
    }
}

// ---------------- combine partials ----------------
// grid: (NH, BATCH), block 128 (one thread per dim)
__global__ __launch_bounds__(128) void attn_reduce(const float* __restrict__ part,
                                                   const int* __restrict__ context_lens,
                                                   float* __restrict__ attn_out) {
    const int h = blockIdx.x;
    const int b = blockIdx.y;
    const int d = threadIdx.x;
    const int kv = h >> 1, g = h & 1;
    const int len = context_lens[b];
    const int nch = (len + CHUNK - 1) / CHUNK;

    const float* pb = part + (size_t)(((b * NKV + kv) * NCHUNK) * 2 + g) * PSTRIDE;
    // chunk i lives at pb + i*2*PSTRIDE
    float M = -1e30f;
    for (int i = 0; i < nch; i++) M = fmaxf(M, pb[(size_t)i * 2 * PSTRIDE]);
    float L = 0.f, acc = 0.f;
    for (int i = 0; i < nch; i++) {
        const float* e = pb + (size_t)i * 2 * PSTRIDE;
        float wgt = __expf(e[0] - M);
        L   += wgt * e[1];
        acc += wgt * e[2 + d];
    }
    attn_out[(size_t)b * QSIZE + h * HD + d] = acc / L;
}

// ---------------- host launcher ----------------
extern "C" void kernel_launch(void* const* d_in, const int* in_sizes, int n_in,
                              void* d_out, int out_size, void* d_ws, size_t ws_size,
                              hipStream_t stream) {
    const float* hidden        = (const float*)d_in[0];
    const int*   positions     = (const int*)d_in[1];
    const float* qkv_w         = (const float*)d_in[2];
    const float* q_norm_w      = (const float*)d_in[3];
    const float* k_norm_w      = (const float*)d_in[4];
    const float* o_w           = (const float*)d_in[5];
    const float* cs_cache      = (const float*)d_in[6];
    float*       k_cache       = (float*)d_in[7];
    float*       v_cache       = (float*)d_in[8];
    const int*   slot_mapping  = (const int*)d_in[9];
    const int*   block_tables  = (const int*)d_in[10];
    const int*   context_lens  = (const int*)d_in[11];
    float*       out           = (float*)d_out;

    char* ws = (char*)d_ws;
    float* qkv      = (float*)(ws);                                   // 16*4096*4   = 256 KiB
    float* attn_out = (float*)(ws + (size_t)BATCH * QKVROWS * 4);     // 16*2048*4   = 128 KiB
    float* part     = (float*)(ws + (size_t)BATCH * QKVROWS * 4
                                  + (size_t)BATCH * QSIZE * 4);       // ~8.3 MiB

    // 1) QKV projection
    gemm_m16<<<dim3(QKVROWS / 16), 256, 0, stream>>>(hidden, qkv_w, qkv, QKVROWS);
    // 2) RMSNorm + RoPE + KV-cache write
    norm_rope_cache<<<dim3(NH + 2 * NKV, BATCH), 64, 0, stream>>>(
        qkv, q_norm_w, k_norm_w, cs_cache, positions, slot_mapping, k_cache, v_cache);
    // 3) paged attention partials
    attn_partial<<<dim3(NCHUNK / 4, NKV, BATCH), 256, 0, stream>>>(
        qkv, k_cache, v_cache, block_tables, context_lens, part);
    // 4) combine partials
    attn_reduce<<<dim3(NH, BATCH), 128, 0, stream>>>(part, context_lens, attn_out);
    // 5) output projection
    gemm_m16<<<dim3(HID / 16), 256, 0, stream>>>(attn_out, o_w, out, HID);
}